// Round 13
// baseline (512.270 us; speedup 1.0000x reference)
//
#include <hip/hip_runtime.h>
#include <hip/hip_bf16.h>
#include <math.h>

typedef __bf16 bf16;
typedef __bf16 bf16x8 __attribute__((ext_vector_type(8)));
typedef float  f32x4  __attribute__((ext_vector_type(4)));

__device__ __forceinline__ float gelu_f(float x) {
    // exact GELU: 0.5*x*(1+erf(x/sqrt(2)))
    return 0.5f * x * (1.0f + erff(x * 0.70710678118654752440f));
}

// ---------------------------------------------------------------------------
// Input-dtype detection. flag: 0 = bf16, 1 = fp32.
// ---------------------------------------------------------------------------
__global__ void detect_k(const unsigned short* __restrict__ h, int* __restrict__ flag)
{
    if (threadIdx.x == 0 && blockIdx.x == 0) {
        int cnt = 0;
        for (int i = 0; i < 256; i += 2) {
            int e = (h[i] >> 7) & 0xFF;
            cnt += (e >= 100 && e <= 140) ? 1 : 0;
        }
        *flag = (cnt >= 96) ? 0 : 1;
    }
}

// ---------------------------------------------------------------------------
// One kernel for all 7 small tensors (mask, b1, b2, g1, be1, g2, be2).
// ---------------------------------------------------------------------------
struct SmallConvArgs {
    const void* src[7];
    bf16* dst[7];
    int n[7];
};
__global__ __launch_bounds__(256) void small_convert_k(SmallConvArgs a,
                                                       const int* __restrict__ flag)
{
    const int seg = blockIdx.y;
    const int i = blockIdx.x * 256 + threadIdx.x;
    if (i >= a.n[seg]) return;
    const float v = (*flag) ? ((const float*)a.src[seg])[i]
                            : (float)((const bf16*)a.src[seg])[i];
    a.dst[seg][i] = (bf16)v;
}

// ---------------------------------------------------------------------------
// Merged convert+transpose for BOTH weights in one launch: z=0 -> w1
// [D,F]->w1T[F,D], z=1 -> w2 [F,D]->w2T[D,F].
// ---------------------------------------------------------------------------
struct WtArgs {
    const void* src[2];
    bf16* dst[2];
    int R[2];
    int C[2];
};
__global__ __launch_bounds__(256) void conv_transpose_w_k(
    WtArgs a, const int* __restrict__ flag)
{
    __shared__ bf16 tile[32][33];
    const int z = blockIdx.z;
    const int R = a.R[z], C = a.C[z];
    const void* in = a.src[z];
    bf16* outT = a.dst[z];
    const int tpr = C / 32;                 // tiles per row
    const int c0 = (blockIdx.x % tpr) * 32;
    const int r0 = (blockIdx.x / tpr) * 32;
    const int tx = threadIdx.x & 31;
    const int ty = threadIdx.x >> 5;        // 0..7
    const bool f32 = (*flag) != 0;
#pragma unroll
    for (int i = 0; i < 32; i += 8) {
        const long idx = (long)(r0 + ty + i) * C + (c0 + tx);
        const float v = f32 ? ((const float*)in)[idx] : (float)((const bf16*)in)[idx];
        tile[ty + i][tx] = (bf16)v;
    }
    __syncthreads();
#pragma unroll
    for (int i = 0; i < 32; i += 8)
        outT[(long)(c0 + ty + i) * R + (r0 + tx)] = tile[tx][ty + i];
}

// ---------------------------------------------------------------------------
// Fused convert + transpose for h: writes h_bf [B,S,D] and hT [B,D,S].
// ---------------------------------------------------------------------------
__global__ __launch_bounds__(256) void conv_transpose_h_k(
    const void* __restrict__ in, bf16* __restrict__ h_bf, bf16* __restrict__ hT,
    int S, int D, const int* __restrict__ flag)
{
    __shared__ bf16 tile[32][33];
    const long sB = (long)S * D;
    const int d0 = blockIdx.x * 32;
    const int s0 = blockIdx.y * 32;
    const int b  = blockIdx.z;
    const int tx = threadIdx.x & 31;
    const int ty = threadIdx.x >> 5;
    const bool f32 = (*flag) != 0;
#pragma unroll
    for (int i = 0; i < 32; i += 8) {
        const long idx = b * sB + (long)(s0 + ty + i) * D + (d0 + tx);
        const float v = f32 ? ((const float*)in)[idx] : (float)((const bf16*)in)[idx];
        const bf16 bv = (bf16)v;
        h_bf[idx] = bv;
        tile[ty + i][tx] = bv;
    }
    __syncthreads();
#pragma unroll
    for (int i = 0; i < 32; i += 8)
        hT[b * sB + (long)(d0 + ty + i) * S + (s0 + tx)] = tile[tx][ty + i];
}

// ---------------------------------------------------------------------------
// global_load_lds 16B: wave-uniform LDS dest + lane*16; per-lane global src.
// ---------------------------------------------------------------------------
__device__ __forceinline__ void gll16(const bf16* g, bf16* l)
{
    __builtin_amdgcn_global_load_lds(
        (const __attribute__((address_space(1))) void*)g,
        (__attribute__((address_space(3))) void*)l, 16, 0, 0);
}

// ---------------------------------------------------------------------------
// NT GEMM, big-tile 2-phase, all-dbuf, 16x16x32 MFMA (R9/R11-proven best:
// 648 TF FFN1, ~423 us total). BMxBN tile, BK=64, 512 threads = 8 waves
// (2x4); per-wave (BM/2)x(BN/4).
//  - GLL width-16 + source-pre-swizzle staging (conflicts 0): lane l of an
//    8-row unit lands at physical chunk l&7 of row l>>3; fetches logical
//    chunk ((l&7)-(l>>3))&7 -> landed layout == (chunk+row)&7 rotate.
//  - dbuf via 4 distinct static __shared__ arrays, issue-early, plain
//    __syncthreads; XCD-aware tile remap (null at L3-fit size, harmless).
// Config search complete (R1-R12): manual pipelines regress (R1/R2/R8,
// closed); 256^2 dbuf > single (R10); XCD swizzle null (R9); 32x32 MFMA
// regresses via 4-way swizzle conflicts, 6.3M cyc (R12). 16x16x32 + rotate
// swizzle is the matched pairing.
// MODE: 0 = scale only, 1 = plain, 2 = bias+GELU, 3 = bias,
//       4 = scale + additive mask[col] (scores+mask fusion; bias=mask row,
//           advanced per blockIdx.z by sBias)
// ---------------------------------------------------------------------------
template <int MODE, int BM, int BN>
__global__ __launch_bounds__(512, 2) void gemm_big(
    const bf16* __restrict__ A, const bf16* __restrict__ Bt,
    bf16* __restrict__ C, const bf16* __restrict__ bias,
    int M, int N, int K, float scale,
    long sA, long sB, long sC, long sBias)
{
    constexpr int WM = BM / 2;
    constexpr int WN = BN / 4;
    constexpr int MI = WM / 16;
    constexpr int NI = WN / 16;

    A  += (long)blockIdx.z * sA;
    Bt += (long)blockIdx.z * sB;
    C  += (long)blockIdx.z * sC;
    if (MODE == 4) bias += (long)blockIdx.z * sBias;

    // ---- XCD-aware tile remap (T1); nwg % 8 == 0 at every call site ----
    const int nx  = gridDim.x;
    const int nwg = nx * gridDim.y;
    const int bid = blockIdx.y * nx + blockIdx.x;
    const int cpx = nwg >> 3;                       // tiles per XCD chunk
    const int sid = (bid & 7) * cpx + (bid >> 3);   // bijective remap
    const int tileM = (sid / nx) * BM;
    const int tileN = (sid % nx) * BN;

    __shared__ __align__(16) bf16 As0[BM * 64];
    __shared__ __align__(16) bf16 As1[BM * 64];
    __shared__ __align__(16) bf16 Bs0[BN * 64];
    __shared__ __align__(16) bf16 Bs1[BN * 64];

    const int t    = threadIdx.x;
    const int lane = t & 63;
    const int wave = t >> 6;
    const int wr   = wave >> 2;
    const int wc   = wave & 3;
    const int quad = lane >> 4;
    const int l16  = lane & 15;

    const int srow   = lane >> 3;
    const int lchunk = ((lane & 7) - srow) & 7;

    f32x4 acc[MI][NI] = {};

    auto swz = [](int row, int chunk) { return row * 64 + (((chunk + row) & 7) * 8); };

    auto stage = [&](bf16* as, bf16* bs, int k0) {
#pragma unroll
        for (int r2 = 0; r2 < BM / 64; ++r2) {
            const int unit = wave * (BM / 64) + r2;
            const int row  = unit * 8 + srow;
            gll16(A + (long)(tileM + row) * K + (k0 + lchunk * 8), as + unit * 512);
        }
#pragma unroll
        for (int r2 = 0; r2 < BN / 64; ++r2) {
            const int unit = wave * (BN / 64) + r2;
            const int row  = unit * 8 + srow;
            gll16(Bt + (long)(tileN + row) * K + (k0 + lchunk * 8), bs + unit * 512);
        }
    };

    auto compute = [&](const bf16* as, const bf16* bs) {
#pragma unroll
        for (int kk = 0; kk < 64; kk += 32) {
            const int chunk = (kk >> 3) + quad;
            bf16x8 af[MI], bfr[NI];
#pragma unroll
            for (int i = 0; i < MI; ++i)
                af[i] = *(const bf16x8*)&as[swz(wr * WM + i * 16 + l16, chunk)];
#pragma unroll
            for (int j = 0; j < NI; ++j)
                bfr[j] = *(const bf16x8*)&bs[swz(wc * WN + j * 16 + l16, chunk)];
#pragma unroll
            for (int mi = 0; mi < MI; ++mi)
#pragma unroll
                for (int ni = 0; ni < NI; ++ni)
                    acc[mi][ni] = __builtin_amdgcn_mfma_f32_16x16x32_bf16(
                        af[mi], bfr[ni], acc[mi][ni], 0, 0, 0);
        }
    };

    stage(As0, Bs0, 0);
    __syncthreads();
    for (int u = 0; u < K / 64; u += 2) {
        const int k1 = (u + 1) * 64;
        const int k2 = (u + 2) * 64;
        if (k1 < K) stage(As1, Bs1, k1);
        compute(As0, Bs0);
        __syncthreads();
        if (k1 < K) {
            if (k2 < K) stage(As0, Bs0, k2);
            compute(As1, Bs1);
            __syncthreads();
        }
    }

#pragma unroll
    for (int mi = 0; mi < MI; ++mi) {
        const int rbase = tileM + wr * WM + mi * 16 + quad * 4;
#pragma unroll
        for (int ni = 0; ni < NI; ++ni) {
            const int col = tileN + wc * WN + ni * 16 + l16;
            float bv = 0.0f;
            if (MODE >= 2) bv = (float)bias[col];   // MODE 2/3 bias, MODE 4 mask
#pragma unroll
            for (int r = 0; r < 4; ++r) {
                float v = acc[mi][ni][r];
                if (MODE == 0) v *= scale;
                if (MODE == 4) v = v * scale + bv;
                if (MODE == 2 || MODE == 3) v += bv;
                if (MODE == 2) v = gelu_f(v);
                C[(long)(rbase + r) * N + col] = (bf16)v;
            }
        }
    }
}

// ---------------------------------------------------------------------------
// Row softmax, in place, vectorized bf16x8 (mask pre-added in scores
// epilogue, MODE 4).
// ---------------------------------------------------------------------------
__global__ __launch_bounds__(256) void softmax_k(
    bf16* __restrict__ scores, int S)
{
    const long rowOff = ((long)blockIdx.y * S + blockIdx.x) * S;
    bf16* row = scores + rowOff;
    const int t = threadIdx.x;

    const bf16x8 r = ((const bf16x8*)row)[t];
    float v[8];
    float mx = -1e30f;
#pragma unroll
    for (int i = 0; i < 8; ++i) {
        v[i] = (float)r[i];
        mx = fmaxf(mx, v[i]);
    }
#pragma unroll
    for (int off = 32; off > 0; off >>= 1)
        mx = fmaxf(mx, __shfl_down(mx, off));
    __shared__ float redm[4];
    if ((t & 63) == 0) redm[t >> 6] = mx;
    __syncthreads();
    mx = fmaxf(fmaxf(redm[0], redm[1]), fmaxf(redm[2], redm[3]));

    float s = 0.0f;
#pragma unroll
    for (int i = 0; i < 8; ++i) { v[i] = __expf(v[i] - mx); s += v[i]; }
#pragma unroll
    for (int off = 32; off > 0; off >>= 1)
        s += __shfl_down(s, off);
    __shared__ float reds[4];
    if ((t & 63) == 0) reds[t >> 6] = s;
    __syncthreads();
    s = reds[0] + reds[1] + reds[2] + reds[3];
    const float inv = 1.0f / s;
    bf16x8 o;
#pragma unroll
    for (int i = 0; i < 8; ++i) o[i] = (bf16)(v[i] * inv);
    ((bf16x8*)row)[t] = o;
}

// ---------------------------------------------------------------------------
// Fused residual + LayerNorm -> bf16 out, vectorized bf16x8.
// ---------------------------------------------------------------------------
__global__ __launch_bounds__(128) void ln_residual_k(
    const bf16* __restrict__ x1, const bf16* __restrict__ x2,
    const bf16* __restrict__ gamma, const bf16* __restrict__ beta,
    bf16* __restrict__ out)
{
    constexpr int D = 1024;
    const long off = (long)blockIdx.x * D;
    const int t = threadIdx.x;
    const bf16x8 a = ((const bf16x8*)(x1 + off))[t];
    const bf16x8 b = ((const bf16x8*)(x2 + off))[t];
    float v[8];
    float s = 0.0f, s2 = 0.0f;
#pragma unroll
    for (int i = 0; i < 8; ++i) {
        v[i] = (float)a[i] + (float)b[i];
        s  += v[i];
        s2 += v[i] * v[i];
    }
#pragma unroll
    for (int o2 = 32; o2 > 0; o2 >>= 1) {
        s  += __shfl_down(s, o2);
        s2 += __shfl_down(s2, o2);
    }
    __shared__ float rs[2], rs2[2];
    if ((t & 63) == 0) { rs[t >> 6] = s; rs2[t >> 6] = s2; }
    __syncthreads();
    s  = rs[0] + rs[1];
    s2 = rs2[0] + rs2[1];
    const float mean = s / (float)D;
    const float var  = s2 / (float)D - mean * mean;
    const float inv  = rsqrtf(var + 1e-5f);
    const bf16x8 g  = ((const bf16x8*)gamma)[t];
    const bf16x8 be = ((const bf16x8*)beta)[t];
    bf16x8 o;
#pragma unroll
    for (int i = 0; i < 8; ++i)
        o[i] = (bf16)((v[i] - mean) * inv * (float)g[i] + (float)be[i]);
    ((bf16x8*)(out + off))[t] = o;
}

// ---------------------------------------------------------------------------
// Final residual + LayerNorm -> d_out with flag-aware store dtype.
// ---------------------------------------------------------------------------
__global__ __launch_bounds__(128) void ln_out_k(
    const bf16* __restrict__ x1, const bf16* __restrict__ x2,
    const bf16* __restrict__ gamma, const bf16* __restrict__ beta,
    void* __restrict__ outv, const int* __restrict__ flag)
{
    constexpr int D = 1024;
    const long off = (long)blockIdx.x * D;
    const int t = threadIdx.x;
    const bf16x8 a = ((const bf16x8*)(x1 + off))[t];
    const bf16x8 b = ((const bf16x8*)(x2 + off))[t];
    float v[8];
    float s = 0.0f, s2 = 0.0f;
#pragma unroll
    for (int i = 0; i < 8; ++i) {
        v[i] = (float)a[i] + (float)b[i];
        s  += v[i];
        s2 += v[i] * v[i];
    }
#pragma unroll
    for (int o2 = 32; o2 > 0; o2 >>= 1) {
        s  += __shfl_down(s, o2);
        s2 += __shfl_down(s2, o2);
    }
    __shared__ float rs[2], rs2[2];
    if ((t & 63) == 0) { rs[t >> 6] = s; rs2[t >> 6] = s2; }
    __syncthreads();
    s  = rs[0] + rs[1];
    s2 = rs2[0] + rs2[1];
    const float mean = s / (float)D;
    const float var  = s2 / (float)D - mean * mean;
    const float inv  = rsqrtf(var + 1e-5f);
    const bf16x8 g  = ((const bf16x8*)gamma)[t];
    const bf16x8 be = ((const bf16x8*)beta)[t];
    if (*flag) {
        f32x4 o1, o2v;
#pragma unroll
        for (int i = 0; i < 4; ++i) {
            o1[i]  = (v[i] - mean) * inv * (float)g[i] + (float)be[i];
            o2v[i] = (v[4 + i] - mean) * inv * (float)g[4 + i] + (float)be[4 + i];
        }
        f32x4* op = (f32x4*)((float*)outv + off);
        op[t * 2]     = o1;
        op[t * 2 + 1] = o2v;
    } else {
        bf16x8 o;
#pragma unroll
        for (int i = 0; i < 8; ++i)
            o[i] = (bf16)((v[i] - mean) * inv * (float)g[i] + (float)be[i]);
        ((bf16x8*)((bf16*)outv + off))[t] = o;
    }
}

// ---------------------------------------------------------------------------
extern "C" void kernel_launch(void* const* d_in, const int* in_sizes, int n_in,
                              void* d_out, int out_size, void* d_ws, size_t ws_size,
                              hipStream_t stream)
{
    constexpr int B = 4, S = 2048, D = 1024, F = 4096;
    constexpr long MB = 1024 * 1024;

    const void* h_raw  = d_in[0];
    const void* mk_raw = d_in[1];
    const void* w1_raw = d_in[2];
    const void* b1_raw = d_in[3];
    const void* w2_raw = d_in[4];
    const void* b2_raw = d_in[5];
    const void* g1_raw = d_in[6];
    const void* be1_raw= d_in[7];
    const void* g2_raw = d_in[8];
    const void* be2_raw= d_in[9];

    // ws layout (liveness-checked overlays), 112 MiB + small tail:
    char* ws = (char*)d_ws;
    bf16* scores = (bf16*)(ws + 0);
    bf16* gact   = (bf16*)(ws + 0);
    bf16* hT     = (bf16*)(ws + 32 * MB);
    bf16* h_bf   = (bf16*)(ws + 48 * MB);
    bf16* y1     = (bf16*)(ws + 64 * MB);
    bf16* w1T    = (bf16*)(ws + 80 * MB);
    bf16* w2T    = (bf16*)(ws + 88 * MB);
    bf16* axf    = (bf16*)(ws + 96 * MB);    // attn, later ffn
    char* sm     = ws + 112 * MB;
    int*  flag   = (int*)(sm);
    bf16* mk_bf  = (bf16*)(sm + 1024);
    bf16* b1_bf  = (bf16*)(sm + 17408 + 1024);
    bf16* b2_bf  = (bf16*)(sm + 25600 + 3072);
    bf16* g1_bf  = (bf16*)(sm + 27648 + 3072);
    bf16* be1_bf = (bf16*)(sm + 29696 + 3072);
    bf16* g2_bf  = (bf16*)(sm + 31744 + 3072);
    bf16* be2_bf = (bf16*)(sm + 33792 + 3072);

    const long SD = (long)S * D;
    const long SS = (long)S * S;

    // 1) detect input dtype (0=bf16, 1=fp32)
    detect_k<<<1, 64, 0, stream>>>((const unsigned short*)h_raw, flag);

    // 2) all 7 small tensors in one convert kernel
    SmallConvArgs sca;
    sca.src[0] = mk_raw;  sca.dst[0] = mk_bf;  sca.n[0] = B * S;
    sca.src[1] = b1_raw;  sca.dst[1] = b1_bf;  sca.n[1] = F;
    sca.src[2] = b2_raw;  sca.dst[2] = b2_bf;  sca.n[2] = D;
    sca.src[3] = g1_raw;  sca.dst[3] = g1_bf;  sca.n[3] = D;
    sca.src[4] = be1_raw; sca.dst[4] = be1_bf; sca.n[4] = D;
    sca.src[5] = g2_raw;  sca.dst[5] = g2_bf;  sca.n[5] = D;
    sca.src[6] = be2_raw; sca.dst[6] = be2_bf; sca.n[6] = D;
    small_convert_k<<<dim3((B * S) / 256, 7), 256, 0, stream>>>(sca, flag);

    // 3) h: fused convert+transpose -> h_bf [B,S,D] and hT [B,D,S]
    conv_transpose_h_k<<<dim3(D / 32, S / 32, B), 256, 0, stream>>>(
        h_raw, h_bf, hT, S, D, flag);

    // 4+5) both weight transposes in ONE launch: w1 [D,F]->w1T, w2 [F,D]->w2T
    WtArgs wa;
    wa.src[0] = w1_raw; wa.dst[0] = w1T; wa.R[0] = D; wa.C[0] = F;
    wa.src[1] = w2_raw; wa.dst[1] = w2T; wa.R[1] = F; wa.C[1] = D;
    conv_transpose_w_k<<<dim3((D / 32) * (F / 32), 1, 2), 256, 0, stream>>>(wa, flag);

    // 6) scores = h @ h^T / 32 + mask[b,col]  (256x256 dbuf, MODE 4 fusion)
    gemm_big<4, 256, 256><<<dim3(S / 256, S / 256, B), 512, 0, stream>>>(
        h_bf, h_bf, scores, mk_bf, S, S, D, 0.03125f, SD, SD, SS, (long)S);

    // 7) softmax rows, in place (mask already added)
    softmax_k<<<dim3(S, B), 256, 0, stream>>>(scores, S);

    // 8) attn = probs @ h (via hT)  [B, S, D]   (256x128 dbuf)
    gemm_big<1, 256, 128><<<dim3(D / 128, S / 256, B), 512, 0, stream>>>(
        scores, hT, axf, nullptr, S, D, S, 1.0f, SS, SD, SD, 0);

    // 9) y1 = LN(h + attn)
    ln_residual_k<<<B * S, 128, 0, stream>>>(h_bf, axf, g1_bf, be1_bf, y1);

    // 10) gact = GELU(y1 @ w1 + b1)  [B*S, F]   (256x256 dbuf)
    gemm_big<2, 256, 256><<<dim3(F / 256, (B * S) / 256, 1), 512, 0, stream>>>(
        y1, w1T, gact, b1_bf, B * S, F, D, 1.0f, 0, 0, 0, 0);

    // 11) ffn = gact @ w2 + b2  [B*S, D]   (256x128 dbuf)
    gemm_big<3, 256, 128><<<dim3(D / 128, (B * S) / 256, 1), 512, 0, stream>>>(
        gact, w2T, axf, b2_bf, B * S, D, F, 1.0f, 0, 0, 0, 0);

    // 12) out = LN(y1 + ffn) -> d_out (flag-aware output dtype)
    ln_out_k<<<B * S, 128, 0, stream>>>(y1, axf, g2_bf, be2_bf, d_out, flag);
}

// Round 14
// 422.010 us; speedup vs baseline: 1.2139x; 1.2139x over previous
//
#include <hip/hip_runtime.h>
#include <hip/hip_bf16.h>
#include <math.h>

typedef __bf16 bf16;
typedef __bf16 bf16x8 __attribute__((ext_vector_type(8)));
typedef float  f32x4  __attribute__((ext_vector_type(4)));

__device__ __forceinline__ float gelu_f(float x) {
    // exact GELU: 0.5*x*(1+erf(x/sqrt(2)))
    return 0.5f * x * (1.0f + erff(x * 0.70710678118654752440f));
}

// ---------------------------------------------------------------------------
// Input-dtype detection. flag: 0 = bf16, 1 = fp32.
// ---------------------------------------------------------------------------
__global__ void detect_k(const unsigned short* __restrict__ h, int* __restrict__ flag)
{
    if (threadIdx.x == 0 && blockIdx.x == 0) {
        int cnt = 0;
        for (int i = 0; i < 256; i += 2) {
            int e = (h[i] >> 7) & 0xFF;
            cnt += (e >= 100 && e <= 140) ? 1 : 0;
        }
        *flag = (cnt >= 96) ? 0 : 1;
    }
}

// ---------------------------------------------------------------------------
// One kernel for all 7 small tensors (mask, b1, b2, g1, be1, g2, be2).
// ---------------------------------------------------------------------------
struct SmallConvArgs {
    const void* src[7];
    bf16* dst[7];
    int n[7];
};
__global__ __launch_bounds__(256) void small_convert_k(SmallConvArgs a,
                                                       const int* __restrict__ flag)
{
    const int seg = blockIdx.y;
    const int i = blockIdx.x * 256 + threadIdx.x;
    if (i >= a.n[seg]) return;
    const float v = (*flag) ? ((const float*)a.src[seg])[i]
                            : (float)((const bf16*)a.src[seg])[i];
    a.dst[seg][i] = (bf16)v;
}

// ---------------------------------------------------------------------------
// Merged convert+transpose for BOTH weights in one launch: z=0 -> w1
// [D,F]->w1T[F,D], z=1 -> w2 [F,D]->w2T[D,F].
// ---------------------------------------------------------------------------
struct WtArgs {
    const void* src[2];
    bf16* dst[2];
    int R[2];
    int C[2];
};
__global__ __launch_bounds__(256) void conv_transpose_w_k(
    WtArgs a, const int* __restrict__ flag)
{
    __shared__ bf16 tile[32][33];
    const int z = blockIdx.z;
    const int R = a.R[z], C = a.C[z];
    const void* in = a.src[z];
    bf16* outT = a.dst[z];
    const int tpr = C / 32;                 // tiles per row
    const int c0 = (blockIdx.x % tpr) * 32;
    const int r0 = (blockIdx.x / tpr) * 32;
    const int tx = threadIdx.x & 31;
    const int ty = threadIdx.x >> 5;        // 0..7
    const bool f32 = (*flag) != 0;
#pragma unroll
    for (int i = 0; i < 32; i += 8) {
        const long idx = (long)(r0 + ty + i) * C + (c0 + tx);
        const float v = f32 ? ((const float*)in)[idx] : (float)((const bf16*)in)[idx];
        tile[ty + i][tx] = (bf16)v;
    }
    __syncthreads();
#pragma unroll
    for (int i = 0; i < 32; i += 8)
        outT[(long)(c0 + ty + i) * R + (r0 + tx)] = tile[tx][ty + i];
}

// ---------------------------------------------------------------------------
// Fused convert + transpose for h: writes h_bf [B,S,D] and hT [B,D,S].
// ---------------------------------------------------------------------------
__global__ __launch_bounds__(256) void conv_transpose_h_k(
    const void* __restrict__ in, bf16* __restrict__ h_bf, bf16* __restrict__ hT,
    int S, int D, const int* __restrict__ flag)
{
    __shared__ bf16 tile[32][33];
    const long sB = (long)S * D;
    const int d0 = blockIdx.x * 32;
    const int s0 = blockIdx.y * 32;
    const int b  = blockIdx.z;
    const int tx = threadIdx.x & 31;
    const int ty = threadIdx.x >> 5;
    const bool f32 = (*flag) != 0;
#pragma unroll
    for (int i = 0; i < 32; i += 8) {
        const long idx = b * sB + (long)(s0 + ty + i) * D + (d0 + tx);
        const float v = f32 ? ((const float*)in)[idx] : (float)((const bf16*)in)[idx];
        const bf16 bv = (bf16)v;
        h_bf[idx] = bv;
        tile[ty + i][tx] = bv;
    }
    __syncthreads();
#pragma unroll
    for (int i = 0; i < 32; i += 8)
        hT[b * sB + (long)(d0 + ty + i) * S + (s0 + tx)] = tile[tx][ty + i];
}

// ---------------------------------------------------------------------------
// global_load_lds 16B: wave-uniform LDS dest + lane*16; per-lane global src.
// ---------------------------------------------------------------------------
__device__ __forceinline__ void gll16(const bf16* g, bf16* l)
{
    __builtin_amdgcn_global_load_lds(
        (const __attribute__((address_space(1))) void*)g,
        (__attribute__((address_space(3))) void*)l, 16, 0, 0);
}

// ---------------------------------------------------------------------------
// NT GEMM, big-tile 2-phase, all-dbuf, 16x16x32 MFMA (R9/R11-proven best:
// 648 TF FFN1, ~423 us total). BMxBN tile, BK=64, 512 threads = 8 waves
// (2x4); per-wave (BM/2)x(BN/4).
//  - GLL width-16 + source-pre-swizzle staging (conflicts 0): lane l of an
//    8-row unit lands at physical chunk l&7 of row l>>3; fetches logical
//    chunk ((l&7)-(l>>3))&7 -> landed layout == (chunk+row)&7 rotate.
//  - dbuf via 4 distinct static __shared__ arrays, issue-early, plain
//    __syncthreads; XCD-aware tile remap (null at L3-fit size, harmless).
// Config search complete (R1-R12): manual pipelines regress (R1/R2/R8,
// closed); 256^2 dbuf > single (R10); XCD swizzle null (R9); 32x32 MFMA
// regresses via 4-way swizzle conflicts (R12). 16x16x32 + rotate swizzle
// is the matched pairing. R13 ran this exact code 1.86x slower with
// IDENTICAL work counters and uniformly-scaled util fractions -> degraded
// container memory throughput; resubmitted unchanged as discriminator.
// MODE: 0 = scale only, 1 = plain, 2 = bias+GELU, 3 = bias,
//       4 = scale + additive mask[col] (scores+mask fusion; bias=mask row,
//           advanced per blockIdx.z by sBias)
// ---------------------------------------------------------------------------
template <int MODE, int BM, int BN>
__global__ __launch_bounds__(512, 2) void gemm_big(
    const bf16* __restrict__ A, const bf16* __restrict__ Bt,
    bf16* __restrict__ C, const bf16* __restrict__ bias,
    int M, int N, int K, float scale,
    long sA, long sB, long sC, long sBias)
{
    constexpr int WM = BM / 2;
    constexpr int WN = BN / 4;
    constexpr int MI = WM / 16;
    constexpr int NI = WN / 16;

    A  += (long)blockIdx.z * sA;
    Bt += (long)blockIdx.z * sB;
    C  += (long)blockIdx.z * sC;
    if (MODE == 4) bias += (long)blockIdx.z * sBias;

    // ---- XCD-aware tile remap (T1); nwg % 8 == 0 at every call site ----
    const int nx  = gridDim.x;
    const int nwg = nx * gridDim.y;
    const int bid = blockIdx.y * nx + blockIdx.x;
    const int cpx = nwg >> 3;                       // tiles per XCD chunk
    const int sid = (bid & 7) * cpx + (bid >> 3);   // bijective remap
    const int tileM = (sid / nx) * BM;
    const int tileN = (sid % nx) * BN;

    __shared__ __align__(16) bf16 As0[BM * 64];
    __shared__ __align__(16) bf16 As1[BM * 64];
    __shared__ __align__(16) bf16 Bs0[BN * 64];
    __shared__ __align__(16) bf16 Bs1[BN * 64];

    const int t    = threadIdx.x;
    const int lane = t & 63;
    const int wave = t >> 6;
    const int wr   = wave >> 2;
    const int wc   = wave & 3;
    const int quad = lane >> 4;
    const int l16  = lane & 15;

    const int srow   = lane >> 3;
    const int lchunk = ((lane & 7) - srow) & 7;

    f32x4 acc[MI][NI] = {};

    auto swz = [](int row, int chunk) { return row * 64 + (((chunk + row) & 7) * 8); };

    auto stage = [&](bf16* as, bf16* bs, int k0) {
#pragma unroll
        for (int r2 = 0; r2 < BM / 64; ++r2) {
            const int unit = wave * (BM / 64) + r2;
            const int row  = unit * 8 + srow;
            gll16(A + (long)(tileM + row) * K + (k0 + lchunk * 8), as + unit * 512);
        }
#pragma unroll
        for (int r2 = 0; r2 < BN / 64; ++r2) {
            const int unit = wave * (BN / 64) + r2;
            const int row  = unit * 8 + srow;
            gll16(Bt + (long)(tileN + row) * K + (k0 + lchunk * 8), bs + unit * 512);
        }
    };

    auto compute = [&](const bf16* as, const bf16* bs) {
#pragma unroll
        for (int kk = 0; kk < 64; kk += 32) {
            const int chunk = (kk >> 3) + quad;
            bf16x8 af[MI], bfr[NI];
#pragma unroll
            for (int i = 0; i < MI; ++i)
                af[i] = *(const bf16x8*)&as[swz(wr * WM + i * 16 + l16, chunk)];
#pragma unroll
            for (int j = 0; j < NI; ++j)
                bfr[j] = *(const bf16x8*)&bs[swz(wc * WN + j * 16 + l16, chunk)];
#pragma unroll
            for (int mi = 0; mi < MI; ++mi)
#pragma unroll
                for (int ni = 0; ni < NI; ++ni)
                    acc[mi][ni] = __builtin_amdgcn_mfma_f32_16x16x32_bf16(
                        af[mi], bfr[ni], acc[mi][ni], 0, 0, 0);
        }
    };

    stage(As0, Bs0, 0);
    __syncthreads();
    for (int u = 0; u < K / 64; u += 2) {
        const int k1 = (u + 1) * 64;
        const int k2 = (u + 2) * 64;
        if (k1 < K) stage(As1, Bs1, k1);
        compute(As0, Bs0);
        __syncthreads();
        if (k1 < K) {
            if (k2 < K) stage(As0, Bs0, k2);
            compute(As1, Bs1);
            __syncthreads();
        }
    }

#pragma unroll
    for (int mi = 0; mi < MI; ++mi) {
        const int rbase = tileM + wr * WM + mi * 16 + quad * 4;
#pragma unroll
        for (int ni = 0; ni < NI; ++ni) {
            const int col = tileN + wc * WN + ni * 16 + l16;
            float bv = 0.0f;
            if (MODE >= 2) bv = (float)bias[col];   // MODE 2/3 bias, MODE 4 mask
#pragma unroll
            for (int r = 0; r < 4; ++r) {
                float v = acc[mi][ni][r];
                if (MODE == 0) v *= scale;
                if (MODE == 4) v = v * scale + bv;
                if (MODE == 2 || MODE == 3) v += bv;
                if (MODE == 2) v = gelu_f(v);
                C[(long)(rbase + r) * N + col] = (bf16)v;
            }
        }
    }
}

// ---------------------------------------------------------------------------
// Row softmax, in place, vectorized bf16x8 (mask pre-added in scores
// epilogue, MODE 4).
// ---------------------------------------------------------------------------
__global__ __launch_bounds__(256) void softmax_k(
    bf16* __restrict__ scores, int S)
{
    const long rowOff = ((long)blockIdx.y * S + blockIdx.x) * S;
    bf16* row = scores + rowOff;
    const int t = threadIdx.x;

    const bf16x8 r = ((const bf16x8*)row)[t];
    float v[8];
    float mx = -1e30f;
#pragma unroll
    for (int i = 0; i < 8; ++i) {
        v[i] = (float)r[i];
        mx = fmaxf(mx, v[i]);
    }
#pragma unroll
    for (int off = 32; off > 0; off >>= 1)
        mx = fmaxf(mx, __shfl_down(mx, off));
    __shared__ float redm[4];
    if ((t & 63) == 0) redm[t >> 6] = mx;
    __syncthreads();
    mx = fmaxf(fmaxf(redm[0], redm[1]), fmaxf(redm[2], redm[3]));

    float s = 0.0f;
#pragma unroll
    for (int i = 0; i < 8; ++i) { v[i] = __expf(v[i] - mx); s += v[i]; }
#pragma unroll
    for (int off = 32; off > 0; off >>= 1)
        s += __shfl_down(s, off);
    __shared__ float reds[4];
    if ((t & 63) == 0) reds[t >> 6] = s;
    __syncthreads();
    s = reds[0] + reds[1] + reds[2] + reds[3];
    const float inv = 1.0f / s;
    bf16x8 o;
#pragma unroll
    for (int i = 0; i < 8; ++i) o[i] = (bf16)(v[i] * inv);
    ((bf16x8*)row)[t] = o;
}

// ---------------------------------------------------------------------------
// Fused residual + LayerNorm -> bf16 out, vectorized bf16x8.
// ---------------------------------------------------------------------------
__global__ __launch_bounds__(128) void ln_residual_k(
    const bf16* __restrict__ x1, const bf16* __restrict__ x2,
    const bf16* __restrict__ gamma, const bf16* __restrict__ beta,
    bf16* __restrict__ out)
{
    constexpr int D = 1024;
    const long off = (long)blockIdx.x * D;
    const int t = threadIdx.x;
    const bf16x8 a = ((const bf16x8*)(x1 + off))[t];
    const bf16x8 b = ((const bf16x8*)(x2 + off))[t];
    float v[8];
    float s = 0.0f, s2 = 0.0f;
#pragma unroll
    for (int i = 0; i < 8; ++i) {
        v[i] = (float)a[i] + (float)b[i];
        s  += v[i];
        s2 += v[i] * v[i];
    }
#pragma unroll
    for (int o2 = 32; o2 > 0; o2 >>= 1) {
        s  += __shfl_down(s, o2);
        s2 += __shfl_down(s2, o2);
    }
    __shared__ float rs[2], rs2[2];
    if ((t & 63) == 0) { rs[t >> 6] = s; rs2[t >> 6] = s2; }
    __syncthreads();
    s  = rs[0] + rs[1];
    s2 = rs2[0] + rs2[1];
    const float mean = s / (float)D;
    const float var  = s2 / (float)D - mean * mean;
    const float inv  = rsqrtf(var + 1e-5f);
    const bf16x8 g  = ((const bf16x8*)gamma)[t];
    const bf16x8 be = ((const bf16x8*)beta)[t];
    bf16x8 o;
#pragma unroll
    for (int i = 0; i < 8; ++i)
        o[i] = (bf16)((v[i] - mean) * inv * (float)g[i] + (float)be[i]);
    ((bf16x8*)(out + off))[t] = o;
}

// ---------------------------------------------------------------------------
// Final residual + LayerNorm -> d_out with flag-aware store dtype.
// ---------------------------------------------------------------------------
__global__ __launch_bounds__(128) void ln_out_k(
    const bf16* __restrict__ x1, const bf16* __restrict__ x2,
    const bf16* __restrict__ gamma, const bf16* __restrict__ beta,
    void* __restrict__ outv, const int* __restrict__ flag)
{
    constexpr int D = 1024;
    const long off = (long)blockIdx.x * D;
    const int t = threadIdx.x;
    const bf16x8 a = ((const bf16x8*)(x1 + off))[t];
    const bf16x8 b = ((const bf16x8*)(x2 + off))[t];
    float v[8];
    float s = 0.0f, s2 = 0.0f;
#pragma unroll
    for (int i = 0; i < 8; ++i) {
        v[i] = (float)a[i] + (float)b[i];
        s  += v[i];
        s2 += v[i] * v[i];
    }
#pragma unroll
    for (int o2 = 32; o2 > 0; o2 >>= 1) {
        s  += __shfl_down(s, o2);
        s2 += __shfl_down(s2, o2);
    }
    __shared__ float rs[2], rs2[2];
    if ((t & 63) == 0) { rs[t >> 6] = s; rs2[t >> 6] = s2; }
    __syncthreads();
    s  = rs[0] + rs[1];
    s2 = rs2[0] + rs2[1];
    const float mean = s / (float)D;
    const float var  = s2 / (float)D - mean * mean;
    const float inv  = rsqrtf(var + 1e-5f);
    const bf16x8 g  = ((const bf16x8*)gamma)[t];
    const bf16x8 be = ((const bf16x8*)beta)[t];
    if (*flag) {
        f32x4 o1, o2v;
#pragma unroll
        for (int i = 0; i < 4; ++i) {
            o1[i]  = (v[i] - mean) * inv * (float)g[i] + (float)be[i];
            o2v[i] = (v[4 + i] - mean) * inv * (float)g[4 + i] + (float)be[4 + i];
        }
        f32x4* op = (f32x4*)((float*)outv + off);
        op[t * 2]     = o1;
        op[t * 2 + 1] = o2v;
    } else {
        bf16x8 o;
#pragma unroll
        for (int i = 0; i < 8; ++i)
            o[i] = (bf16)((v[i] - mean) * inv * (float)g[i] + (float)be[i]);
        ((bf16x8*)((bf16*)outv + off))[t] = o;
    }
}

// ---------------------------------------------------------------------------
extern "C" void kernel_launch(void* const* d_in, const int* in_sizes, int n_in,
                              void* d_out, int out_size, void* d_ws, size_t ws_size,
                              hipStream_t stream)
{
    constexpr int B = 4, S = 2048, D = 1024, F = 4096;
    constexpr long MB = 1024 * 1024;

    const void* h_raw  = d_in[0];
    const void* mk_raw = d_in[1];
    const void* w1_raw = d_in[2];
    const void* b1_raw = d_in[3];
    const void* w2_raw = d_in[4];
    const void* b2_raw = d_in[5];
    const void* g1_raw = d_in[6];
    const void* be1_raw= d_in[7];
    const void* g2_raw = d_in[8];
    const void* be2_raw= d_in[9];

    // ws layout (liveness-checked overlays), 112 MiB + small tail:
    char* ws = (char*)d_ws;
    bf16* scores = (bf16*)(ws + 0);
    bf16* gact   = (bf16*)(ws + 0);
    bf16* hT     = (bf16*)(ws + 32 * MB);
    bf16* h_bf   = (bf16*)(ws + 48 * MB);
    bf16* y1     = (bf16*)(ws + 64 * MB);
    bf16* w1T    = (bf16*)(ws + 80 * MB);
    bf16* w2T    = (bf16*)(ws + 88 * MB);
    bf16* axf    = (bf16*)(ws + 96 * MB);    // attn, later ffn
    char* sm     = ws + 112 * MB;
    int*  flag   = (int*)(sm);
    bf16* mk_bf  = (bf16*)(sm + 1024);
    bf16* b1_bf  = (bf16*)(sm + 17408 + 1024);
    bf16* b2_bf  = (bf16*)(sm + 25600 + 3072);
    bf16* g1_bf  = (bf16*)(sm + 27648 + 3072);
    bf16* be1_bf = (bf16*)(sm + 29696 + 3072);
    bf16* g2_bf  = (bf16*)(sm + 31744 + 3072);
    bf16* be2_bf = (bf16*)(sm + 33792 + 3072);

    const long SD = (long)S * D;
    const long SS = (long)S * S;

    // 1) detect input dtype (0=bf16, 1=fp32)
    detect_k<<<1, 64, 0, stream>>>((const unsigned short*)h_raw, flag);

    // 2) all 7 small tensors in one convert kernel
    SmallConvArgs sca;
    sca.src[0] = mk_raw;  sca.dst[0] = mk_bf;  sca.n[0] = B * S;
    sca.src[1] = b1_raw;  sca.dst[1] = b1_bf;  sca.n[1] = F;
    sca.src[2] = b2_raw;  sca.dst[2] = b2_bf;  sca.n[2] = D;
    sca.src[3] = g1_raw;  sca.dst[3] = g1_bf;  sca.n[3] = D;
    sca.src[4] = be1_raw; sca.dst[4] = be1_bf; sca.n[4] = D;
    sca.src[5] = g2_raw;  sca.dst[5] = g2_bf;  sca.n[5] = D;
    sca.src[6] = be2_raw; sca.dst[6] = be2_bf; sca.n[6] = D;
    small_convert_k<<<dim3((B * S) / 256, 7), 256, 0, stream>>>(sca, flag);

    // 3) h: fused convert+transpose -> h_bf [B,S,D] and hT [B,D,S]
    conv_transpose_h_k<<<dim3(D / 32, S / 32, B), 256, 0, stream>>>(
        h_raw, h_bf, hT, S, D, flag);

    // 4+5) both weight transposes in ONE launch: w1 [D,F]->w1T, w2 [F,D]->w2T
    WtArgs wa;
    wa.src[0] = w1_raw; wa.dst[0] = w1T; wa.R[0] = D; wa.C[0] = F;
    wa.src[1] = w2_raw; wa.dst[1] = w2T; wa.R[1] = F; wa.C[1] = D;
    conv_transpose_w_k<<<dim3((D / 32) * (F / 32), 1, 2), 256, 0, stream>>>(wa, flag);

    // 6) scores = h @ h^T / 32 + mask[b,col]  (256x256 dbuf, MODE 4 fusion)
    gemm_big<4, 256, 256><<<dim3(S / 256, S / 256, B), 512, 0, stream>>>(
        h_bf, h_bf, scores, mk_bf, S, S, D, 0.03125f, SD, SD, SS, (long)S);

    // 7) softmax rows, in place (mask already added)
    softmax_k<<<dim3(S, B), 256, 0, stream>>>(scores, S);

    // 8) attn = probs @ h (via hT)  [B, S, D]   (256x128 dbuf)
    gemm_big<1, 256, 128><<<dim3(D / 128, S / 256, B), 512, 0, stream>>>(
        scores, hT, axf, nullptr, S, D, S, 1.0f, SS, SD, SD, 0);

    // 9) y1 = LN(h + attn)
    ln_residual_k<<<B * S, 128, 0, stream>>>(h_bf, axf, g1_bf, be1_bf, y1);

    // 10) gact = GELU(y1 @ w1 + b1)  [B*S, F]   (256x256 dbuf)
    gemm_big<2, 256, 256><<<dim3(F / 256, (B * S) / 256, 1), 512, 0, stream>>>(
        y1, w1T, gact, b1_bf, B * S, F, D, 1.0f, 0, 0, 0, 0);

    // 11) ffn = gact @ w2 + b2  [B*S, D]   (256x128 dbuf)
    gemm_big<3, 256, 128><<<dim3(D / 128, (B * S) / 256, 1), 512, 0, stream>>>(
        gact, w2T, axf, b2_bf, B * S, D, F, 1.0f, 0, 0, 0, 0);

    // 12) out = LN(y1 + ffn) -> d_out (flag-aware output dtype)
    ln_out_k<<<B * S, 128, 0, stream>>>(y1, axf, g2_bf, be2_bf, d_out, flag);
}